// Round 2
// baseline (539.440 us; speedup 1.0000x reference)
//
#include <hip/hip_runtime.h>

#define HW 16384
#define Nn 4096

typedef __bf16 bf16x8 __attribute__((ext_vector_type(8)));
typedef unsigned short us8t __attribute__((ext_vector_type(8)));
typedef float f32x4 __attribute__((ext_vector_type(4)));
typedef unsigned int u32x4 __attribute__((ext_vector_type(4)));

__device__ __forceinline__ unsigned short f2bf(float f) {
    unsigned int u = __float_as_uint(f);
    u = (u + 0x7fffu + ((u >> 16) & 1u)) >> 16;  // RNE
    return (unsigned short)u;
}
__device__ __forceinline__ float bf2f(unsigned int h) {
    return __uint_as_float(h << 16);
}
// pack two f32 -> two bf16 (round-half-up) in 3 VALU ops (2 add + 1 v_perm)
__device__ __forceinline__ unsigned int pack2bf(float lo, float hi) {
    const unsigned int u0 = __float_as_uint(lo) + 0x8000u;
    const unsigned int u1 = __float_as_uint(hi) + 0x8000u;
    return __builtin_amdgcn_perm(u1, u0, 0x07060302u);
}
__device__ __forceinline__ f32x4 mfma16(us8t a, us8t b, f32x4 c) {
    return __builtin_amdgcn_mfma_f32_16x16x32_bf16(
        __builtin_bit_cast(bf16x8, a), __builtin_bit_cast(bf16x8, b), c, 0, 0, 0);
}

// ---------------- K0: weights -> bf16, transposed [d][c] ----------------
__global__ __launch_bounds__(256) void k_wt(const float* __restrict__ W1,
                                            const float* __restrict__ W2,
                                            const float* __restrict__ Wp,
                                            unsigned short* __restrict__ WT) {
    const int m = blockIdx.x >> 8;
    const int d = blockIdx.x & 255;
    const int c = threadIdx.x;
    const float* W = (m == 0) ? W1 : (m == 1) ? W2 : Wp;
    WT[m * 65536 + d * 256 + c] = f2bf(W[c * 256 + d]);
}

// ---------------- K1 (k_pix): S[bl][p][d] = sum_c f[b][c][p] * W1[c][d], bf16 ----------------
// A = W1T (M=d=256, from L2), B = fT (N=p=64, via LDS), 256 thr / 4 waves m-split.
__global__ __launch_bounds__(256) void k_pix(const float* __restrict__ f,
                                             const unsigned short* __restrict__ W1T,
                                             unsigned short* __restrict__ S, int b0) {
    __shared__ __align__(16) unsigned int Asb[64 * 132];  // fT bf16 [64 p][264 c], pitch 528B=33*16

    const int blk = blockIdx.x;
    const int bl = blk >> 8;
    const int b = b0 + bl;
    const int p0 = (blk & 255) << 6;
    const int t = threadIdx.x;
    const int lane = t & 63;
    const int w = t >> 6;
    const int mrow = lane & 15;
    const int kg = (lane >> 4) << 3;

    const float* fb = f + ((size_t)b << 22);

    // ---- stage whole 64p x 256c tile -> LDS bf16 (single barrier) ----
    const int sp = (t & 15) << 2;   // local p-quad
    const int c8 = (t >> 4) << 3;   // c-octet
#pragma unroll
    for (int pass = 0; pass < 2; ++pass) {
        const int c0 = c8 + (pass << 7);
        f32x4 v[8];
#pragma unroll
        for (int i = 0; i < 8; ++i)
            v[i] = *(const f32x4*)(fb + ((size_t)(c0 + i) << 14) + p0 + sp);
#pragma unroll
        for (int j = 0; j < 4; ++j) {
            u32x4 pk;
            pk.x = pack2bf(v[0][j], v[1][j]);
            pk.y = pack2bf(v[2][j], v[3][j]);
            pk.z = pack2bf(v[4][j], v[5][j]);
            pk.w = pack2bf(v[6][j], v[7][j]);
            *(u32x4*)&Asb[(sp + j) * 132 + (c0 >> 1)] = pk;
        }
    }

    f32x4 acc[4][4];
#pragma unroll
    for (int i = 0; i < 4; ++i)
#pragma unroll
        for (int j = 0; j < 4; ++j) acc[i][j] = (f32x4){0.f, 0.f, 0.f, 0.f};

    const unsigned short* AW = W1T + (((w << 6) + mrow) << 8) + kg;  // + mt*16*256 + k0
    us8t aN[4];
#pragma unroll
    for (int mt = 0; mt < 4; ++mt) aN[mt] = *(const us8t*)(AW + (mt << 12));

    __syncthreads();

    const unsigned short* Bl = (const unsigned short*)Asb + mrow * 264 + kg;
#pragma unroll
    for (int k0 = 0; k0 < 256; k0 += 32) {
        us8t aC[4];
#pragma unroll
        for (int mt = 0; mt < 4; ++mt) aC[mt] = aN[mt];
        if (k0 < 224) {
#pragma unroll
            for (int mt = 0; mt < 4; ++mt)
                aN[mt] = *(const us8t*)(AW + (mt << 12) + k0 + 32);
        }
        us8t bF[4];
#pragma unroll
        for (int nt = 0; nt < 4; ++nt)
            bF[nt] = *(const us8t*)(Bl + nt * 16 * 264 + k0);
#pragma unroll
        for (int mt = 0; mt < 4; ++mt)
#pragma unroll
            for (int nt = 0; nt < 4; ++nt)
                acc[mt][nt] = mfma16(aC[mt], bF[nt], acc[mt][nt]);
    }

    // ---- store: lane holds 4 consecutive d -> packed b64 stores ----
    unsigned short* Sp = S + ((((size_t)bl << 14) + p0 + mrow) << 8) + (w << 6) + ((lane >> 4) << 2);
#pragma unroll
    for (int nt = 0; nt < 4; ++nt) {
        unsigned short* Sr = Sp + ((size_t)(nt << 4) << 8);
#pragma unroll
        for (int mt = 0; mt < 4; ++mt) {
            uint2 pk;
            pk.x = pack2bf(acc[mt][nt][0], acc[mt][nt][1]);
            pk.y = pack2bf(acc[mt][nt][2], acc[mt][nt][3]);
            *(uint2*)(Sr + (mt << 4)) = pk;
        }
    }
}

// ---------------- K2 (k_gather): h[bl][n][c] = relu(bilerp(S) + b1), bf16 ----------------
// one wave per point: 4 coalesced 512B row reads, no LDS, no barriers
__global__ __launch_bounds__(256) void k_gather(const unsigned short* __restrict__ S,
                                                const float* __restrict__ verts,
                                                const int* __restrict__ iszp,
                                                const float* __restrict__ b1,
                                                unsigned short* __restrict__ h, int b0) {
    const int t = threadIdx.x;
    const int lane = t & 63;
    const int w = t >> 6;
    const int blk = blockIdx.x;
    const int bl = blk >> 10;
    const int n = ((blk & 1023) << 2) + w;
    const int b = b0 + bl;

    const float isz = (float)iszp[0];
    const size_t vo = ((size_t)b * Nn + n) << 1;
    const float vx = verts[vo];
    const float vy = verts[vo + 1];
    const float gs = 127.0f / (isz - 1.0f);
    const float ix = fminf(fmaxf(vx * gs, 0.0f), 127.0f);
    const float iy = fminf(fmaxf(vy * gs, 0.0f), 127.0f);
    const float x0 = floorf(ix), y0 = floorf(iy);
    const float wx = ix - x0, wy = iy - y0;
    const int x0i = (int)x0, y0i = (int)y0;
    const int x1i = min(x0i + 1, 127), y1i = min(y0i + 1, 127);
    const float w00 = (1.0f - wx) * (1.0f - wy);
    const float w01 = wx * (1.0f - wy);
    const float w10 = (1.0f - wx) * wy;
    const float w11 = wx * wy;

    const unsigned short* Sb = S + ((size_t)bl << 22);
    const int co = lane << 2;  // channel offset (shorts)
    const uint2 a0 = *(const uint2*)(Sb + (((size_t)(y0i << 7) + x0i) << 8) + co);
    const uint2 a1 = *(const uint2*)(Sb + (((size_t)(y0i << 7) + x1i) << 8) + co);
    const uint2 a2 = *(const uint2*)(Sb + (((size_t)(y1i << 7) + x0i) << 8) + co);
    const uint2 a3 = *(const uint2*)(Sb + (((size_t)(y1i << 7) + x1i) << 8) + co);
    const float4 bb = *(const float4*)(b1 + co);

    float d0 = w00 * bf2f(a0.x & 0xffffu) + w01 * bf2f(a1.x & 0xffffu) +
               w10 * bf2f(a2.x & 0xffffu) + w11 * bf2f(a3.x & 0xffffu) + bb.x;
    float d1 = w00 * bf2f(a0.x >> 16) + w01 * bf2f(a1.x >> 16) +
               w10 * bf2f(a2.x >> 16) + w11 * bf2f(a3.x >> 16) + bb.y;
    float d2 = w00 * bf2f(a0.y & 0xffffu) + w01 * bf2f(a1.y & 0xffffu) +
               w10 * bf2f(a2.y & 0xffffu) + w11 * bf2f(a3.y & 0xffffu) + bb.z;
    float d3 = w00 * bf2f(a0.y >> 16) + w01 * bf2f(a1.y >> 16) +
               w10 * bf2f(a2.y >> 16) + w11 * bf2f(a3.y >> 16) + bb.w;
    d0 = fmaxf(d0, 0.0f);
    d1 = fmaxf(d1, 0.0f);
    d2 = fmaxf(d2, 0.0f);
    d3 = fmaxf(d3, 0.0f);
    uint2 pk;
    pk.x = pack2bf(d0, d1);
    pk.y = pack2bf(d2, d3);
    *(uint2*)(h + (((size_t)bl * Nn + n) << 8) + co) = pk;
}

// ---------------- K3 (k_mlp): out = (h@W2 + b2 + posenc) @ Wp + bp ----------------
__global__ __launch_bounds__(256) void k_mlp(const unsigned short* __restrict__ h,
                                             const float* __restrict__ verts,
                                             const int* __restrict__ iszp,
                                             const unsigned short* __restrict__ W2T,
                                             const unsigned short* __restrict__ WpT,
                                             const float* __restrict__ b2,
                                             const float* __restrict__ bpv,
                                             float* __restrict__ out, int b0) {
    __shared__ __align__(16) unsigned short gT[64][264];
    __shared__ float vps[64][2];
    __shared__ float b2s[256], bps[256];

    const int blk = blockIdx.x;
    const int bl = blk >> 6;
    const int b = b0 + bl;
    const int n0 = (blk & 63) << 6;
    const int t = threadIdx.x;
    const int lane = t & 63;
    const int w = t >> 6;

    b2s[t] = b2[t];
    bps[t] = bpv[t];
    if (t < 64) {
        const float isz = (float)iszp[0];
        const size_t vo = ((size_t)b * Nn + n0 + t) << 1;
        vps[t][0] = verts[vo] / isz;
        vps[t][1] = verts[vo + 1] / isz;
    }

    const int mrow = lane & 15;
    const int kg = (lane >> 4) << 3;
    const int r0 = (lane >> 4) << 2;
    const int n0w = w << 6;

    // ---- GEMM2: vfeat = h @ W2 ; A-frags direct from global (L3-hot h) ----
    const unsigned short* hb = h + (((size_t)bl * Nn + n0 + mrow) << 8) + kg;
    const unsigned short* B2 = W2T + ((n0w + mrow) << 8) + kg;
    f32x4 acc[4][4];
#pragma unroll
    for (int i = 0; i < 4; ++i)
#pragma unroll
        for (int j = 0; j < 4; ++j) acc[i][j] = (f32x4){0.f, 0.f, 0.f, 0.f};

    us8t aN[4], bN[4];
#pragma unroll
    for (int mt = 0; mt < 4; ++mt) aN[mt] = *(const us8t*)(hb + (mt << 12));
#pragma unroll
    for (int nt = 0; nt < 4; ++nt) bN[nt] = *(const us8t*)(B2 + (nt << 12));
#pragma unroll
    for (int k0 = 0; k0 < 256; k0 += 32) {
        us8t aC[4], bC[4];
#pragma unroll
        for (int i = 0; i < 4; ++i) { aC[i] = aN[i]; bC[i] = bN[i]; }
        if (k0 < 224) {
#pragma unroll
            for (int mt = 0; mt < 4; ++mt) aN[mt] = *(const us8t*)(hb + (mt << 12) + k0 + 32);
#pragma unroll
            for (int nt = 0; nt < 4; ++nt) bN[nt] = *(const us8t*)(B2 + (nt << 12) + k0 + 32);
        }
#pragma unroll
        for (int mt = 0; mt < 4; ++mt)
#pragma unroll
            for (int nt = 0; nt < 4; ++nt)
                acc[mt][nt] = mfma16(aC[mt], bC[nt], acc[mt][nt]);
    }
    __syncthreads();  // vps/b2s ready; gT free

    // ---- epilogue: g = vfeat + b2 + posenc -> gT bf16 ----
    const float C2 = -0.20762050593046f;  // -log2(10000)/64
#pragma unroll
    for (int nt = 0; nt < 4; ++nt) {
        const int col = n0w + (nt << 4) + mrow;
        const float bias2 = b2s[col];
        const int ci = col & 127;
        const float dv = exp2f((float)(ci >> 1) * C2) * 1000.0f;
        const int sel = col >> 7;
#pragma unroll
        for (int mt = 0; mt < 4; ++mt)
#pragma unroll
            for (int j = 0; j < 4; ++j) {
                const int row = (mt << 4) + r0 + j;
                const float ang = vps[row][sel] * dv;
                const float pe = (col & 1) ? __cosf(ang) : __sinf(ang);
                const float val = acc[mt][nt][j] + bias2 + pe;
                gT[row][col] = (unsigned short)((__float_as_uint(val) + 0x8000u) >> 16);
            }
    }
    __syncthreads();

    // ---- GEMM3: out = g @ Wp + bp ----
#pragma unroll
    for (int i = 0; i < 4; ++i)
#pragma unroll
        for (int j = 0; j < 4; ++j) acc[i][j] = (f32x4){0.f, 0.f, 0.f, 0.f};
    const unsigned short* Bp = WpT + ((n0w + mrow) << 8) + kg;
#pragma unroll
    for (int nt = 0; nt < 4; ++nt) bN[nt] = *(const us8t*)(Bp + (nt << 12));
    const unsigned short* Al = &gT[mrow][kg];
#pragma unroll
    for (int k0 = 0; k0 < 256; k0 += 32) {
        us8t bC[4];
#pragma unroll
        for (int i = 0; i < 4; ++i) bC[i] = bN[i];
        if (k0 < 224) {
#pragma unroll
            for (int nt = 0; nt < 4; ++nt) bN[nt] = *(const us8t*)(Bp + (nt << 12) + k0 + 32);
        }
        us8t aC[4];
#pragma unroll
        for (int mt = 0; mt < 4; ++mt)
            aC[mt] = *(const us8t*)(Al + mt * 16 * 264 + k0);
#pragma unroll
        for (int mt = 0; mt < 4; ++mt)
#pragma unroll
            for (int nt = 0; nt < 4; ++nt)
                acc[mt][nt] = mfma16(aC[mt], bC[nt], acc[mt][nt]);
    }

    float* ob = out + (((size_t)b * Nn + n0) << 8);
#pragma unroll
    for (int nt = 0; nt < 4; ++nt) {
        const int col = n0w + (nt << 4) + mrow;
        const float bb = bps[col];
#pragma unroll
        for (int mt = 0; mt < 4; ++mt)
#pragma unroll
            for (int j = 0; j < 4; ++j) {
                const int row = (mt << 4) + r0 + j;
                ob[((size_t)row << 8) + col] = acc[mt][nt][j] + bb;
            }
    }
}

extern "C" void kernel_launch(void* const* d_in, const int* in_sizes, int n_in,
                              void* d_out, int out_size, void* d_ws, size_t ws_size,
                              hipStream_t stream) {
    const float* f = (const float*)d_in[0];
    const float* verts = (const float*)d_in[1];
    const int* isz = (const int*)d_in[2];
    const float* W1 = (const float*)d_in[3];
    const float* b1 = (const float*)d_in[4];
    const float* W2 = (const float*)d_in[5];
    const float* b2 = (const float*)d_in[6];
    const float* Wp = (const float*)d_in[7];
    const float* bp = (const float*)d_in[8];
    float* out = (float*)d_out;

    unsigned short* WT = (unsigned short*)d_ws;
    const size_t S_OFF = 1u << 20;
    const size_t perS = (size_t)HW * 256 * 2;  // 8 MB / batch
    const size_t perH = (size_t)Nn * 256 * 2;  // 2 MB / batch
    const size_t avail = (ws_size > S_OFF) ? (ws_size - S_OFF) : 0;
    int nbMax = (int)(avail / (perS + perH));
    if (nbMax < 1) nbMax = 1;
    if (nbMax > 16) nbMax = 16;
    unsigned short* S = (unsigned short*)((char*)d_ws + S_OFF);
    unsigned short* Hb = (unsigned short*)((char*)d_ws + S_OFF + (size_t)nbMax * perS);

    k_wt<<<dim3(768), dim3(256), 0, stream>>>(W1, W2, Wp, WT);
    for (int b0 = 0; b0 < 16; b0 += nbMax) {
        const int nb = (16 - b0 < nbMax) ? (16 - b0) : nbMax;
        k_pix<<<dim3(nb * 256), dim3(256), 0, stream>>>(f, WT, S, b0);
        k_gather<<<dim3(nb * 1024), dim3(256), 0, stream>>>(S, verts, isz, b1, Hb, b0);
        k_mlp<<<dim3(nb * 64), dim3(256), 0, stream>>>(Hb, verts, isz, WT + 65536, WT + 131072,
                                                       b2, bp, out, b0);
    }
}

// Round 3
// 529.446 us; speedup vs baseline: 1.0189x; 1.0189x over previous
//
#include <hip/hip_runtime.h>

#define HW 16384
#define Nn 4096
#define PITCH 19  // dwords per 32-c row slice (odd: breaks bank aliasing; forbids b128 reads)

typedef __bf16 bf16x8 __attribute__((ext_vector_type(8)));
typedef unsigned short us8t __attribute__((ext_vector_type(8)));
typedef float f32x4 __attribute__((ext_vector_type(4)));
typedef float f32x2 __attribute__((ext_vector_type(2)));
typedef unsigned int u32x4 __attribute__((ext_vector_type(4)));

__device__ __forceinline__ unsigned short f2bf(float f) {
    unsigned int u = __float_as_uint(f);
    u = (u + 0x7fffu + ((u >> 16) & 1u)) >> 16;  // RNE
    return (unsigned short)u;
}
__device__ __forceinline__ float bf2f(unsigned int h) {
    return __uint_as_float(h << 16);
}
// pack two f32 -> two bf16 (round-half-up): 2 add + 1 v_perm
__device__ __forceinline__ unsigned int pack2bf(float lo, float hi) {
    const unsigned int u0 = __float_as_uint(lo) + 0x8000u;
    const unsigned int u1 = __float_as_uint(hi) + 0x8000u;
    return __builtin_amdgcn_perm(u1, u0, 0x07060302u);
}
__device__ __forceinline__ f32x4 mfma16(us8t a, us8t b, f32x4 c) {
    return __builtin_amdgcn_mfma_f32_16x16x32_bf16(
        __builtin_bit_cast(bf16x8, a), __builtin_bit_cast(bf16x8, b), c, 0, 0, 0);
}

// ---------------- K0: weights -> bf16, transposed [d][c] ----------------
__global__ __launch_bounds__(256) void k_wt(const float* __restrict__ W1,
                                            const float* __restrict__ W2,
                                            const float* __restrict__ Wp,
                                            unsigned short* __restrict__ WT) {
    const int m = blockIdx.x >> 8;
    const int d = blockIdx.x & 255;
    const int c = threadIdx.x;
    const float* W = (m == 0) ? W1 : (m == 1) ? W2 : Wp;
    WT[m * 65536 + d * 256 + c] = f2bf(W[c * 256 + d]);
}

// ---------------- K1 (k_pix): S[bl][p][d] = sum_c f[b][c][p] * W1[c][d], bf16 ----------------
// 1024 threads (16 waves: 4 d-slices x 4 p-slices), tile 256p x 256d, k-step 32c.
// f reads: 512B contiguous per instruction, 1KB per c-row per block per step (DRAM-friendly).
// Double-buffered LDS (1 barrier/step) + depth-2 register pipeline on staging loads.
__global__ __launch_bounds__(1024) void k_pix(const float* __restrict__ f,
                                              const unsigned short* __restrict__ W1T,
                                              unsigned short* __restrict__ S, int b0) {
    __shared__ unsigned int Asb[2][256 * PITCH];  // 2 x 19456 B, fT bf16 [256 p][32 c]

    const int blk = blockIdx.x;
    const int bl = blk >> 6;
    const int b = b0 + bl;
    const int p0 = (blk & 63) << 8;
    const int t = threadIdx.x;
    const int lane = t & 63;
    const int w = t >> 6;

    const float* fb = f + ((size_t)b << 22) + p0;

    // ---- staging assignment: thread covers 4 c-rows x 2 p (f32x2 each) ----
    const int c4 = (t >> 7) << 2;        // c group base: 0,4,...,28
    const int sc2 = (t >> 7) << 1;       // u32 col base: 0,2,...,14
    const int sp = (t & 127) << 1;       // p row: 0..254 even

    f32x2 vst[2][4];

#define ISSUE(ts, set)                                                            \
    {                                                                             \
        const float* fp = fb + ((size_t)(((ts) << 5) + c4) << 14) + sp;           \
        vst[set][0] = *(const f32x2*)(fp);                                        \
        vst[set][1] = *(const f32x2*)(fp + (1 << 14));                            \
        vst[set][2] = *(const f32x2*)(fp + (2 << 14));                            \
        vst[set][3] = *(const f32x2*)(fp + (3 << 14));                            \
    }

#define PACKW(ts)                                                                 \
    {                                                                             \
        const int set_ = (ts) & 1;                                                \
        unsigned int* Bf = Asb[(ts) & 1];                                         \
        _Pragma("unroll") for (int j = 0; j < 2; ++j) {                           \
            unsigned int* row = Bf + (sp + j) * PITCH + sc2;                      \
            row[0] = pack2bf(vst[set_][0][j], vst[set_][1][j]);                   \
            row[1] = pack2bf(vst[set_][2][j], vst[set_][3][j]);                   \
        }                                                                         \
    }

    // ---- MFMA assignment ----
    const int mrow = lane & 15;
    const int quad = lane >> 4;
    const int dw = (w & 3) << 6;   // wave's d slice
    const int pw = (w >> 2) << 6;  // wave's p slice

    f32x4 acc[4][4];
#pragma unroll
    for (int i = 0; i < 4; ++i)
#pragma unroll
        for (int j = 0; j < 4; ++j) acc[i][j] = (f32x4){0.f, 0.f, 0.f, 0.f};

    const unsigned short* AW = W1T + ((dw + mrow) << 8) + (quad << 3);

    // prologue: fill pipeline
    ISSUE(0, 0);
    ISSUE(1, 1);
    PACKW(0);
    __syncthreads();

#pragma unroll
    for (int s = 0; s < 8; ++s) {
        if (s < 6) ISSUE(s + 2, s & 1);
        // A-frags from L2-hot W1T
        us8t afr[4];
#pragma unroll
        for (int mt = 0; mt < 4; ++mt)
            afr[mt] = *(const us8t*)(AW + (mt << 12) + (s << 5));
        // B-frags from LDS (b32 reads; odd pitch -> <=3-way conflicts)
        const unsigned int* Bb = Asb[s & 1] + (pw + mrow) * PITCH + (quad << 2);
#pragma unroll
        for (int nt = 0; nt < 4; ++nt) {
            u32x4 tmp;
            const unsigned int* Br = Bb + nt * 16 * PITCH;
            tmp.x = Br[0];
            tmp.y = Br[1];
            tmp.z = Br[2];
            tmp.w = Br[3];
            const us8t bfr = __builtin_bit_cast(us8t, tmp);
#pragma unroll
            for (int mt = 0; mt < 4; ++mt)
                acc[mt][nt] = mfma16(afr[mt], bfr, acc[mt][nt]);
        }
        if (s < 7) {
            PACKW(s + 1);
            __syncthreads();
        }
    }

    // ---- store: lane holds 4 consecutive d -> packed b64 stores ----
    unsigned short* Sp = S + ((((size_t)bl << 14) + p0 + pw + mrow) << 8) + dw + (quad << 2);
#pragma unroll
    for (int nt = 0; nt < 4; ++nt) {
        unsigned short* Sr = Sp + ((size_t)(nt << 4) << 8);
#pragma unroll
        for (int mt = 0; mt < 4; ++mt) {
            uint2 pk;
            pk.x = pack2bf(acc[mt][nt][0], acc[mt][nt][1]);
            pk.y = pack2bf(acc[mt][nt][2], acc[mt][nt][3]);
            *(uint2*)(Sr + (mt << 4)) = pk;
        }
    }
#undef ISSUE
#undef PACKW
}

// ---------------- K2 (k_gather): h[bl][n][c] = relu(bilerp(S) + b1), bf16 ----------------
__global__ __launch_bounds__(256) void k_gather(const unsigned short* __restrict__ S,
                                                const float* __restrict__ verts,
                                                const int* __restrict__ iszp,
                                                const float* __restrict__ b1,
                                                unsigned short* __restrict__ h, int b0) {
    const int t = threadIdx.x;
    const int lane = t & 63;
    const int w = t >> 6;
    const int blk = blockIdx.x;
    const int bl = blk >> 10;
    const int n = ((blk & 1023) << 2) + w;
    const int b = b0 + bl;

    const float isz = (float)iszp[0];
    const size_t vo = ((size_t)b * Nn + n) << 1;
    const float vx = verts[vo];
    const float vy = verts[vo + 1];
    const float gs = 127.0f / (isz - 1.0f);
    const float ix = fminf(fmaxf(vx * gs, 0.0f), 127.0f);
    const float iy = fminf(fmaxf(vy * gs, 0.0f), 127.0f);
    const float x0 = floorf(ix), y0 = floorf(iy);
    const float wx = ix - x0, wy = iy - y0;
    const int x0i = (int)x0, y0i = (int)y0;
    const int x1i = min(x0i + 1, 127), y1i = min(y0i + 1, 127);
    const float w00 = (1.0f - wx) * (1.0f - wy);
    const float w01 = wx * (1.0f - wy);
    const float w10 = (1.0f - wx) * wy;
    const float w11 = wx * wy;

    const unsigned short* Sb = S + ((size_t)bl << 22);
    const int co = lane << 2;
    const uint2 a0 = *(const uint2*)(Sb + (((size_t)(y0i << 7) + x0i) << 8) + co);
    const uint2 a1 = *(const uint2*)(Sb + (((size_t)(y0i << 7) + x1i) << 8) + co);
    const uint2 a2 = *(const uint2*)(Sb + (((size_t)(y1i << 7) + x0i) << 8) + co);
    const uint2 a3 = *(const uint2*)(Sb + (((size_t)(y1i << 7) + x1i) << 8) + co);
    const float4 bb = *(const float4*)(b1 + co);

    float d0 = w00 * bf2f(a0.x & 0xffffu) + w01 * bf2f(a1.x & 0xffffu) +
               w10 * bf2f(a2.x & 0xffffu) + w11 * bf2f(a3.x & 0xffffu) + bb.x;
    float d1 = w00 * bf2f(a0.x >> 16) + w01 * bf2f(a1.x >> 16) +
               w10 * bf2f(a2.x >> 16) + w11 * bf2f(a3.x >> 16) + bb.y;
    float d2 = w00 * bf2f(a0.y & 0xffffu) + w01 * bf2f(a1.y & 0xffffu) +
               w10 * bf2f(a2.y & 0xffffu) + w11 * bf2f(a3.y & 0xffffu) + bb.z;
    float d3 = w00 * bf2f(a0.y >> 16) + w01 * bf2f(a1.y >> 16) +
               w10 * bf2f(a2.y >> 16) + w11 * bf2f(a3.y >> 16) + bb.w;
    d0 = fmaxf(d0, 0.0f);
    d1 = fmaxf(d1, 0.0f);
    d2 = fmaxf(d2, 0.0f);
    d3 = fmaxf(d3, 0.0f);
    uint2 pk;
    pk.x = pack2bf(d0, d1);
    pk.y = pack2bf(d2, d3);
    *(uint2*)(h + (((size_t)bl * Nn + n) << 8) + co) = pk;
}

// ---------------- K3 (k_mlp): out = (h@W2 + b2 + posenc) @ Wp + bp ----------------
__global__ __launch_bounds__(256) void k_mlp(const unsigned short* __restrict__ h,
                                             const float* __restrict__ verts,
                                             const int* __restrict__ iszp,
                                             const unsigned short* __restrict__ W2T,
                                             const unsigned short* __restrict__ WpT,
                                             const float* __restrict__ b2,
                                             const float* __restrict__ bpv,
                                             float* __restrict__ out, int b0) {
    __shared__ __align__(16) unsigned short gT[64][264];
    __shared__ float vps[64][2];
    __shared__ float b2s[256], bps[256];

    const int blk = blockIdx.x;
    const int bl = blk >> 6;
    const int b = b0 + bl;
    const int n0 = (blk & 63) << 6;
    const int t = threadIdx.x;
    const int lane = t & 63;
    const int w = t >> 6;

    b2s[t] = b2[t];
    bps[t] = bpv[t];
    if (t < 64) {
        const float isz = (float)iszp[0];
        const size_t vo = ((size_t)b * Nn + n0 + t) << 1;
        vps[t][0] = verts[vo] / isz;
        vps[t][1] = verts[vo + 1] / isz;
    }

    const int mrow = lane & 15;
    const int kg = (lane >> 4) << 3;
    const int r0 = (lane >> 4) << 2;
    const int n0w = w << 6;

    // ---- GEMM2: vfeat = h @ W2 ; A-frags direct from global (L3-hot h) ----
    const unsigned short* hb = h + (((size_t)bl * Nn + n0 + mrow) << 8) + kg;
    const unsigned short* B2 = W2T + ((n0w + mrow) << 8) + kg;
    f32x4 acc[4][4];
#pragma unroll
    for (int i = 0; i < 4; ++i)
#pragma unroll
        for (int j = 0; j < 4; ++j) acc[i][j] = (f32x4){0.f, 0.f, 0.f, 0.f};

    us8t aN[4], bN[4];
#pragma unroll
    for (int mt = 0; mt < 4; ++mt) aN[mt] = *(const us8t*)(hb + (mt << 12));
#pragma unroll
    for (int nt = 0; nt < 4; ++nt) bN[nt] = *(const us8t*)(B2 + (nt << 12));
#pragma unroll
    for (int k0 = 0; k0 < 256; k0 += 32) {
        us8t aC[4], bC[4];
#pragma unroll
        for (int i = 0; i < 4; ++i) { aC[i] = aN[i]; bC[i] = bN[i]; }
        if (k0 < 224) {
#pragma unroll
            for (int mt = 0; mt < 4; ++mt) aN[mt] = *(const us8t*)(hb + (mt << 12) + k0 + 32);
#pragma unroll
            for (int nt = 0; nt < 4; ++nt) bN[nt] = *(const us8t*)(B2 + (nt << 12) + k0 + 32);
        }
#pragma unroll
        for (int mt = 0; mt < 4; ++mt)
#pragma unroll
            for (int nt = 0; nt < 4; ++nt)
                acc[mt][nt] = mfma16(aC[mt], bC[nt], acc[mt][nt]);
    }
    __syncthreads();

    // ---- epilogue: g = vfeat + b2 + posenc -> gT bf16 ----
    const float C2 = -0.20762050593046f;  // -log2(10000)/64
#pragma unroll
    for (int nt = 0; nt < 4; ++nt) {
        const int col = n0w + (nt << 4) + mrow;
        const float bias2 = b2s[col];
        const int ci = col & 127;
        const float dv = exp2f((float)(ci >> 1) * C2) * 1000.0f;
        const int sel = col >> 7;
#pragma unroll
        for (int mt = 0; mt < 4; ++mt)
#pragma unroll
            for (int j = 0; j < 4; ++j) {
                const int row = (mt << 4) + r0 + j;
                const float ang = vps[row][sel] * dv;
                const float pe = (col & 1) ? __cosf(ang) : __sinf(ang);
                const float val = acc[mt][nt][j] + bias2 + pe;
                gT[row][col] = (unsigned short)((__float_as_uint(val) + 0x8000u) >> 16);
            }
    }
    __syncthreads();

    // ---- GEMM3: out = g @ Wp + bp ----
#pragma unroll
    for (int i = 0; i < 4; ++i)
#pragma unroll
        for (int j = 0; j < 4; ++j) acc[i][j] = (f32x4){0.f, 0.f, 0.f, 0.f};
    const unsigned short* Bp = WpT + ((n0w + mrow) << 8) + kg;
#pragma unroll
    for (int nt = 0; nt < 4; ++nt) bN[nt] = *(const us8t*)(Bp + (nt << 12));
    const unsigned short* Al = &gT[mrow][kg];
#pragma unroll
    for (int k0 = 0; k0 < 256; k0 += 32) {
        us8t bC[4];
#pragma unroll
        for (int i = 0; i < 4; ++i) bC[i] = bN[i];
        if (k0 < 224) {
#pragma unroll
            for (int nt = 0; nt < 4; ++nt) bN[nt] = *(const us8t*)(Bp + (nt << 12) + k0 + 32);
        }
        us8t aC[4];
#pragma unroll
        for (int mt = 0; mt < 4; ++mt)
            aC[mt] = *(const us8t*)(Al + mt * 16 * 264 + k0);
#pragma unroll
        for (int mt = 0; mt < 4; ++mt)
#pragma unroll
            for (int nt = 0; nt < 4; ++nt)
                acc[mt][nt] = mfma16(aC[mt], bC[nt], acc[mt][nt]);
    }

    float* ob = out + (((size_t)b * Nn + n0) << 8);
#pragma unroll
    for (int nt = 0; nt < 4; ++nt) {
        const int col = n0w + (nt << 4) + mrow;
        const float bb = bps[col];
#pragma unroll
        for (int mt = 0; mt < 4; ++mt)
#pragma unroll
            for (int j = 0; j < 4; ++j) {
                const int row = (mt << 4) + r0 + j;
                ob[((size_t)row << 8) + col] = acc[mt][nt][j] + bb;
            }
    }
}

extern "C" void kernel_launch(void* const* d_in, const int* in_sizes, int n_in,
                              void* d_out, int out_size, void* d_ws, size_t ws_size,
                              hipStream_t stream) {
    const float* f = (const float*)d_in[0];
    const float* verts = (const float*)d_in[1];
    const int* isz = (const int*)d_in[2];
    const float* W1 = (const float*)d_in[3];
    const float* b1 = (const float*)d_in[4];
    const float* W2 = (const float*)d_in[5];
    const float* b2 = (const float*)d_in[6];
    const float* Wp = (const float*)d_in[7];
    const float* bp = (const float*)d_in[8];
    float* out = (float*)d_out;

    unsigned short* WT = (unsigned short*)d_ws;
    const size_t S_OFF = 1u << 20;
    const size_t perS = (size_t)HW * 256 * 2;  // 8 MB / batch
    const size_t perH = (size_t)Nn * 256 * 2;  // 2 MB / batch
    const size_t avail = (ws_size > S_OFF) ? (ws_size - S_OFF) : 0;
    int nbMax = (int)(avail / (perS + perH));
    if (nbMax < 1) nbMax = 1;
    if (nbMax > 16) nbMax = 16;
    unsigned short* S = (unsigned short*)((char*)d_ws + S_OFF);
    unsigned short* Hb = (unsigned short*)((char*)d_ws + S_OFF + (size_t)nbMax * perS);

    k_wt<<<dim3(768), dim3(256), 0, stream>>>(W1, W2, Wp, WT);
    for (int b0 = 0; b0 < 16; b0 += nbMax) {
        const int nb = (16 - b0 < nbMax) ? (16 - b0) : nbMax;
        k_pix<<<dim3(nb * 64), dim3(1024), 0, stream>>>(f, WT, S, b0);
        k_gather<<<dim3(nb * 1024), dim3(256), 0, stream>>>(S, verts, isz, b1, Hb, b0);
        k_mlp<<<dim3(nb * 64), dim3(256), 0, stream>>>(Hb, verts, isz, WT + 65536, WT + 131072,
                                                       b2, bp, out, b0);
    }
}